// Round 12
// baseline (580.081 us; speedup 1.0000x reference)
//
#include <hip/hip_runtime.h>

#define NBATCH 2
#define NPTS   8192
#define NPT    (NBATCH*NPTS)
#define KNN    9
#define SEG    32
#define SEGN   (NPTS/SEG)
#define SCAP   8
#define SSTR   9

typedef unsigned short u16;
typedef unsigned int   u32;
typedef short bf16x8 __attribute__((ext_vector_type(8)));
typedef float f32x4  __attribute__((ext_vector_type(4)));

__device__ __forceinline__ float wred(float v){
#pragma unroll
  for(int o=32;o>0;o>>=1) v += __shfl_down(v,o);
  return v;
}

__device__ __forceinline__ u16 f2b(float f){
  u32 u = __float_as_uint(f);
  return (u16)((u + 0x7fffu + ((u>>16)&1u)) >> 16);
}

__device__ __forceinline__ float bumpup(float x){
  u32 u = __float_as_uint(x);
  if(u == 0x80000000u) u = 1u;
  else if((int)u >= 0) u += 1u;
  else u -= 1u;
  return __uint_as_float(u);
}

// ---------------- build point-major feature matrix [pt][196] + xs table ----------------
__global__ __launch_bounds__(256) void k_build_xin(
    const float* __restrict__ feats, const float* __restrict__ cost,
    const float* __restrict__ flow, const float* __restrict__ xyz,
    float* __restrict__ xin, float4* __restrict__ xs)
{
  __shared__ float buf[196][67];
  int t = threadIdx.x;
  int pt0 = blockIdx.x*64;
  int b = pt0 >> 13, n0 = pt0 & (NPTS-1);
  int lane = t & 63, grp = t >> 6;
  const float* f  = feats + (size_t)b*128*NPTS + n0 + lane;
  const float* cv = cost  + (size_t)b*64 *NPTS + n0 + lane;
  const float* fl = flow  + (size_t)b*3  *NPTS + n0 + lane;
  for(int c=grp; c<128; c+=4) buf[c][lane]      = f[(size_t)c*NPTS];
  for(int c=grp; c<64;  c+=4) buf[128+c][lane]  = cv[(size_t)c*NPTS];
  if(grp<3) buf[192+grp][lane] = fl[(size_t)grp*NPTS];
  else      buf[195][lane] = 0.f;
  if(t < 64){
    int pt = pt0 + t;
    const float* p = xyz + (size_t)b*NPTS*3 + 3*(pt & (NPTS-1));
    float x=p[0], y=p[1], z=p[2];
    float s = __fadd_rn(__fadd_rn(__fmul_rn(x,x),__fmul_rn(y,y)),__fmul_rn(z,z));
    xs[pt] = make_float4(x,y,z,s);
  }
  __syncthreads();
  for(int e=t; e<64*49; e+=256){
    int p = e/49, q = e-p*49;
    float4 v = make_float4(buf[4*q][p], buf[4*q+1][p], buf[4*q+2][p], buf[4*q+3][p]);
    *(float4*)(xin + (size_t)(pt0+p)*196 + 4*q) = v;
  }
}

// ---------------- knn pass A: 9th-smallest over stride-16 sample ----------------
__global__ __launch_bounds__(256) void k_thr(
    const float4* __restrict__ xs, float* __restrict__ thr)
{
  __shared__ float md[4][64][9];
  int t = threadIdx.x, lane = t & 63, wave = t >> 6;
  int qb = blockIdx.x;
  int b = qb >> 7;
  int n = (qb & 127)*64 + lane;
  const float4* xb4 = xs + (size_t)b*NPTS;
  float4 q = xb4[n];
  float qx=q.x, qy=q.y, qz=q.z, qs=q.w;
  float bd[KNN];
#pragma unroll
  for(int i=0;i<KNN;i++) bd[i]=__builtin_inff();
  for(int i=0;i<128;i++){
    int m = (wave*128 + i)*16;
    float4 c = xb4[m];
    float dot = fmaf(c.z,qz, fmaf(c.y,qy, __fmul_rn(c.x,qx)));
    float d = __fsub_rn(__fadd_rn(qs,c.w), __fmul_rn(2.0f,dot));
    if(d < bd[KNN-1]){
      bd[KNN-1]=d;
#pragma unroll
      for(int r=KNN-2;r>=0;r--){
        if(bd[r+1] < bd[r]){ float td=bd[r]; bd[r]=bd[r+1]; bd[r+1]=td; }
      }
    }
  }
#pragma unroll
  for(int i=0;i<KNN;i++) md[wave][lane][i]=bd[i];
  __syncthreads();
  if(t < 64){
    float b2[KNN];
#pragma unroll
    for(int i=0;i<KNN;i++) b2[i]=__builtin_inff();
    for(int w=0;w<4;w++){
#pragma unroll
      for(int i=0;i<KNN;i++){
        float d = md[w][t][i];
        if(d < b2[KNN-1]){
          b2[KNN-1]=d;
#pragma unroll
          for(int r=KNN-2;r>=0;r--){
            if(b2[r+1] < b2[r]){ float td=b2[r]; b2[r]=b2[r+1]; b2[r+1]=td; }
          }
        }
      }
    }
    thr[(b<<13) + (qb & 127)*64 + t] = b2[KNN-1];
  }
}

// ---------------- knn pass B: index-only push-buffer top-9 ----------------
__global__ __launch_bounds__(256) void k_knn_part(
    const float4* __restrict__ xs, const float* __restrict__ thr,
    int* __restrict__ pi)
{
  __shared__ int sqi[256*SSTR];
  int t = threadIdx.x;
  int seg = blockIdx.x & (SEG-1);
  int qc  = blockIdx.x >> 5;
  int b = qc >> 5;
  int n = (qc & 31)*256 + t;
  int pt = (b<<13) + n;
  const float4* xb4 = xs + (size_t)b*NPTS;
  float4 q = xb4[n];
  float qx=q.x, qy=q.y, qz=q.z, qs=q.w;
  float init = bumpup(thr[pt]);
  float bd[KNN]; int bi[KNN];
#pragma unroll
  for(int i=0;i<KNN;i++){ bd[i]=init; bi[i]=0x7fffffff; }
  float cut = init;
  int cnt = 0;
  int* msi = sqi + t*SSTR;
  auto flush = [&](){
    for(int i=0;i<cnt;i++){
      int id = msi[i];
      float4 c = xb4[id];
      float dot = fmaf(c.z,qz, fmaf(c.y,qy, __fmul_rn(c.x,qx)));
      float d = __fsub_rn(__fadd_rn(qs,c.w), __fmul_rn(2.0f,dot));
      if(d < bd[KNN-1]){
        bd[KNN-1]=d; bi[KNN-1]=id;
#pragma unroll
        for(int r=KNN-2;r>=0;r--){
          if(bd[r+1] < bd[r]){
            float td=bd[r]; bd[r]=bd[r+1]; bd[r+1]=td;
            int ti=bi[r]; bi[r]=bi[r+1]; bi[r+1]=ti;
          }
        }
      }
    }
    cnt = 0;
    cut = bd[KNN-1];
  };
  const int m0 = seg*SEGN;
  for(int j0=0; j0<SEGN; j0+=8){
    float dv[8];
#pragma unroll
    for(int u=0;u<8;u++){
      float4 c = xb4[m0+j0+u];                 // wave-uniform address -> broadcast
      float dot = fmaf(c.z,qz, fmaf(c.y,qy, __fmul_rn(c.x,qx)));
      dv[u] = __fsub_rn(__fadd_rn(qs,c.w), __fmul_rn(2.0f,dot));
    }
#pragma unroll
    for(int u=0;u<8;u++){
      if(dv[u] < cut){
        msi[cnt] = m0+j0+u; cnt++;
        if(cnt==SCAP) flush();
      }
    }
  }
  flush();
  size_t base = ((size_t)pt*SEG + seg)*KNN;
#pragma unroll
  for(int i=0;i<KNN;i++) pi[base+i]=bi[i];
}

// ---------------- merge (recompute d, skip sentinels) + g-moment partials ----------------
__global__ __launch_bounds__(256) void k_knn_merge(
    const float4* __restrict__ xs, const int* __restrict__ pi,
    int* __restrict__ idxo, float* __restrict__ gpart)
{
  __shared__ float red[4][9];
  int t = threadIdx.x;
  int pt = blockIdx.x*256 + t;
  int b = pt >> 13;
  const float4* xb4 = xs + (size_t)b*NPTS;
  float4 q = xb4[pt & (NPTS-1)];
  float qx=q.x, qy=q.y, qz=q.z, qs=q.w;
  const int4* ip = (const int4*)(pi + (size_t)pt*SEG*KNN);
  float bd[KNN]; int bi[KNN];
#pragma unroll
  for(int i=0;i<KNN;i++){ bd[i]=__builtin_inff(); bi[i]=0x7fffffff; }
  for(int v=0; v<SEG*KNN/4; v++){
    int4 iv = ip[v];
    int ii[4] = {iv.x,iv.y,iv.z,iv.w};
#pragma unroll
    for(int u=0;u<4;u++){
      int id = ii[u];
      if(id != 0x7fffffff){
        float4 c = xb4[id];
        float dot = fmaf(c.z,qz, fmaf(c.y,qy, __fmul_rn(c.x,qx)));
        float d = __fsub_rn(__fadd_rn(qs,c.w), __fmul_rn(2.0f,dot));
        if(d < bd[KNN-1]){
          bd[KNN-1]=d; bi[KNN-1]=id;
#pragma unroll
          for(int i=KNN-2;i>=0;i--){
            if(bd[i+1] < bd[i]){
              float td=bd[i]; bd[i]=bd[i+1]; bd[i+1]=td;
              int ti=bi[i]; bi[i]=bi[i+1]; bi[i+1]=ti;
            }
          }
        }
      }
    }
  }
#pragma unroll
  for(int r=0;r<KNN;r++) idxo[pt*KNN + r] = bi[r];
  float mom[9];
#pragma unroll
  for(int i=0;i<9;i++) mom[i]=0.f;
#pragma unroll
  for(int r=0;r<KNN;r++){
    int m = bi[r];
    float4 c = xb4[m];
    float gx=c.x-qx, gy=c.y-qy, gz=c.z-qz;
    mom[0]+=gx; mom[1]+=gy; mom[2]+=gz;
    mom[3]=fmaf(gx,gx,mom[3]); mom[4]=fmaf(gy,gy,mom[4]); mom[5]=fmaf(gz,gz,mom[5]);
    mom[6]=fmaf(gx,gy,mom[6]); mom[7]=fmaf(gx,gz,mom[7]); mom[8]=fmaf(gy,gz,mom[8]);
  }
  int wave = t>>6, lane = t&63;
#pragma unroll
  for(int i=0;i<9;i++){
    float s = wred(mom[i]);
    if(lane==0) red[wave][i]=s;
  }
  __syncthreads();
  if(t<9)
    gpart[blockIdx.x*9 + t] = red[0][t]+red[1][t]+red[2][t]+red[3][t];
}

// ---------------- wn stage1+2 fused, BOTH layers: analytic st1, h1 on the fly ----------------
__global__ __launch_bounds__(256) void k_wn23a2(
    const float* __restrict__ xyz, const int* __restrict__ idx,
    const float* __restrict__ gpart, float cnt,
    const float* __restrict__ W1a, const float* __restrict__ B1a,
    const float* __restrict__ W2a, const float* __restrict__ B2a,
    const float* __restrict__ W1b, const float* __restrict__ B1b,
    const float* __restrict__ W2b, const float* __restrict__ B2b,
    float* __restrict__ houta, float* __restrict__ houtb,
    float* __restrict__ parta, float* __restrict__ partb)
{
  __shared__ float mom[9];
  __shared__ float stl[2][16];
  __shared__ float red[4][2][8];
  int t = threadIdx.x;
  if(t<9){
    float s=0.f;
    for(int r=0;r<64;r++) s += gpart[r*9+t];
    mom[t]=s;
  }
  __syncthreads();
  if(t<16){
    int L = t>>3, j = t&7;
    const float* W1 = L? W1b : W1a;
    const float* B1 = L? B1b : B1a;
    float inv = 1.0f/cnt;
    float w0=W1[3*j], w1=W1[3*j+1], w2=W1[3*j+2], bb=B1[j];
    float Eg0=mom[0]*inv, Eg1=mom[1]*inv, Eg2=mom[2]*inv;
    float Mxx=mom[3]*inv, Myy=mom[4]*inv, Mzz=mom[5]*inv;
    float Mxy=mom[6]*inv, Mxz=mom[7]*inv, Myz=mom[8]*inv;
    float mu_lin = w0*Eg0 + w1*Eg1 + w2*Eg2;
    float mean = mu_lin + bb;
    float e2 = w0*w0*Mxx + w1*w1*Myy + w2*w2*Mzz
             + 2.f*(w0*w1*Mxy + w0*w2*Mxz + w1*w2*Myz)
             + 2.f*bb*mu_lin + bb*bb;
    float var = e2 - mean*mean;
    stl[L][j] = mean;
    stl[L][8+j] = 1.0f/sqrtf(var + 1e-5f);
  }
  __syncthreads();
  int e = blockIdx.x*256 + t;
  int pt = e/KNN;
  int b = pt>>13, n = pt & (NPTS-1);
  int m = idx[e];
  const float* xb = xyz + (size_t)b*NPTS*3;
  float gx = xb[3*m]-xb[3*n], gy = xb[3*m+1]-xb[3*n+1], gz = xb[3*m+2]-xb[3*n+2];
  int wave = t>>6, lane = t&63;
#pragma unroll
  for(int L=0; L<2; L++){
    const float* W1 = L? W1b : W1a;
    const float* B1 = L? B1b : B1a;
    const float* W2 = L? W2b : W2a;
    const float* B2 = L? B2b : B2a;
    float* hout = L? houtb : houta;
    float* part = L? partb : parta;
    float x[8];
#pragma unroll
    for(int j=0;j<8;j++){
      float d = fmaf(gz, W1[3*j+2], fmaf(gy, W1[3*j+1], gx*W1[3*j]));
      float v = d + B1[j];
      v = (v - stl[L][j])*stl[L][8+j];
      x[j] = v>0.f? v : 0.f;
    }
    float v[8];
#pragma unroll
    for(int j=0;j<8;j++){
      float d = 0.f;
#pragma unroll
      for(int i=0;i<8;i++) d = fmaf(x[i], W2[j*8+i], d);
      v[j] = d + B2[j];
      hout[(size_t)e*8 + j] = v[j];
    }
#pragma unroll
    for(int j=0;j<8;j++){
      float s = wred(v[j]);
      float q = wred(v[j]*v[j]);
      if(lane==0){ red[wave][0][j]=s; red[wave][1][j]=q; }
    }
    __syncthreads();
    if(t < 16){
      int isq = t>>3, c = t&7;
      part[blockIdx.x*16 + t] =
        red[0][isq][c]+red[1][isq][c]+red[2][isq][c]+red[3][isq][c];
    }
    __syncthreads();
  }
}

// ---------------- wn stage 3, BOTH layers, fused stats-finalize preamble ----------------
__global__ __launch_bounds__(256) void k_wn23_2(
    const float* __restrict__ hina, const float* __restrict__ pina,
    const float* __restrict__ hinb, const float* __restrict__ pinb,
    int nb, float cnt,
    const float* __restrict__ Wa, const float* __restrict__ Ba,
    const float* __restrict__ Wb, const float* __restrict__ Bb,
    float* __restrict__ houta, float* __restrict__ houtb,
    float* __restrict__ parta, float* __restrict__ partb)
{
  __shared__ float sa[256], qa[256];
  __shared__ float stl[16];
  __shared__ float red[4][2][16];
  int t = threadIdx.x;
  int e = blockIdx.x*256 + t;
  int wave = t>>6, lane = t&63;
#pragma unroll
  for(int L=0; L<2; L++){
    const float* hin = L? hinb : hina;
    const float* pin = L? pinb : pina;
    const float* W   = L? Wb : Wa;
    const float* Bv  = L? Bb : Ba;
    float* hout = L? houtb : houta;
    float* part = L? partb : parta;
    {
      int c = t % 8;
      int r0 = t / 8;
      float s=0.f, q=0.f;
      for(int r=r0; r<nb; r+=32){
        s += pin[r*16 + c];
        q += pin[r*16 + 8 + c];
      }
      sa[t]=s; qa[t]=q;
      __syncthreads();
      if(t < 8){
        for(int g=1; g<32; g++){ s += sa[t+g*8]; q += qa[t+g*8]; }
        float mean = s/cnt;
        float var  = q/cnt - mean*mean;
        stl[t]   = mean;
        stl[8+t] = 1.0f/sqrtf(var + 1e-5f);
      }
      __syncthreads();
    }
    float x[8];
#pragma unroll
    for(int i=0;i<8;i++){
      float v = (hin[(size_t)e*8 + i] - stl[i])*stl[8+i];
      x[i] = v>0.f? v : 0.f;
    }
    float v[16];
#pragma unroll
    for(int j=0;j<16;j++){
      float d = 0.f;
#pragma unroll
      for(int i=0;i<8;i++) d = fmaf(x[i], W[j*8+i], d);
      v[j] = d + Bv[j];
      hout[(size_t)e*16 + j] = v[j];
    }
#pragma unroll
    for(int j=0;j<16;j++){
      float s = wred(v[j]);
      float q = wred(v[j]*v[j]);
      if(lane==0){ red[wave][0][j]=s; red[wave][1][j]=q; }
    }
    __syncthreads();
    if(t < 32){
      int isq = t>>4, c = t&15;
      part[blockIdx.x*32 + t] =
        red[0][isq][c]+red[1][isq][c]+red[2][isq][c]+red[3][isq][c];
    }
    __syncthreads();
  }
}

// ---------------- finalize st3 for both layers ----------------
__global__ __launch_bounds__(256) void k_fin2(
    const float* __restrict__ pa, const float* __restrict__ pb,
    float* __restrict__ sta, float* __restrict__ stb, int nb, float cnt)
{
  __shared__ float sa[256], qa[256];
  int t = threadIdx.x;
  const int C = 16;
#pragma unroll
  for(int L=0; L<2; L++){
    const float* partial = L? pb : pa;
    float* st = L? stb : sta;
    int c = t % C;
    int r0 = t / C;
    int stride = 256 / C;
    float s=0.f, q=0.f;
    for(int r=r0; r<nb; r+=stride){
      s += partial[r*2*C + c];
      q += partial[r*2*C + C + c];
    }
    sa[t]=s; qa[t]=q;
    __syncthreads();
    if(t < C){
      for(int g=1; g<stride; g++){ s += sa[t+g*C]; q += qa[t+g*C]; }
      float mean = s/cnt;
      float var  = q/cnt - mean*mean;
      st[t]   = mean;
      st[C+t] = 1.0f/sqrtf(var + 1e-5f);
    }
    __syncthreads();
  }
}

// ---------------- finalize stats (generic) ----------------
__global__ __launch_bounds__(256) void k_fin(
    const float* __restrict__ partial, float* __restrict__ st,
    int C, int nb, float cnt)
{
  __shared__ float sa[256], qa[256];
  int t = threadIdx.x;
  int c = t % C;
  int r0 = t / C;
  int stride = 256 / C;
  float s=0.f, q=0.f;
  for(int r=r0; r<nb; r+=stride){
    s += partial[r*2*C + c];
    q += partial[r*2*C + C + c];
  }
  sa[t]=s; qa[t]=q;
  __syncthreads();
  if(t < C){
    for(int g=1; g<stride; g++){ s += sa[t+g*C]; q += qa[t+g*C]; }
    float mean = s/cnt;
    float var  = q/cnt - mean*mean;
    st[t]   = mean;
    st[C+t] = 1.0f/sqrtf(var + 1e-5f);
  }
}

// ---------------- prep both W: f32 -> bf16, K-padded ----------------
__global__ __launch_bounds__(256) void k_prepW2(
    const float* __restrict__ W0, u16* __restrict__ Wh0,
    const float* __restrict__ W1, u16* __restrict__ Wh1)
{
  int e = blockIdx.x*256 + threadIdx.x;
  const int N0 = 128*3200;
  if(e < N0){
    int o = e / 3200, k = e - o*3200;
    float w = (k < 3168) ? W0[o*3168 + k] : 0.f;
    Wh0[e] = f2b(w);
  } else {
    int e1 = e - N0;
    if(e1 >= 128*2112) return;
    int o = e1 / 2112, k = e1 - o*2112;
    float w = (k < 2096) ? W1[o*2096 + k] : 0.f;
    Wh1[e1] = f2b(w);
  }
}

// ---------------- build A (gather [+bn+leaky] + weightnet einsum) ----------------
template<int CIN, int XSTRIDE, int KP, bool BN>
__global__ __launch_bounds__(256) void k_buildA(
    const float* __restrict__ xin, const float* __restrict__ xyz,
    const int* __restrict__ idx, const float* __restrict__ wpre,
    const float* __restrict__ st3, const float* __restrict__ bnst,
    u16* __restrict__ Abuf, int c0)
{
  constexpr int P = 16;
  constexpr int CPTS = CIN-3;
  constexpr int CPAD = KP/16;
  __shared__ float wm[P][KNN][16];
  __shared__ float gxs[P][KNN][3];
  __shared__ int   si[P][KNN];
  __shared__ float sm3[16], sr3[16];
  int t = threadIdx.x;
  int pt0 = c0 + blockIdx.x*P;
  int b = pt0 >> 13;
  const float* xb = xyz + (size_t)b*NPTS*3;
  if(t<16){ sm3[t]=st3[t]; sr3[t]=st3[16+t]; }
  for(int e=t; e<P*KNN; e+=256){
    int p = e/KNN, k = e - p*KNN;
    int n = (pt0+p)&(NPTS-1);
    int m = idx[(pt0+p)*KNN+k];
    si[p][k]=m;
    gxs[p][k][0]=xb[3*m]  -xb[3*n];
    gxs[p][k][1]=xb[3*m+1]-xb[3*n+1];
    gxs[p][k][2]=xb[3*m+2]-xb[3*n+2];
  }
  __syncthreads();
  for(int e=t; e<P*KNN*16; e+=256){
    int p = e/(KNN*16); int r = e - p*(KNN*16); int k = r>>4, wn = r&15;
    float v = (wpre[((size_t)(pt0+p)*KNN + k)*16 + wn] - sm3[wn]) * sr3[wn];
    wm[p][k][wn] = v>0.f? v:0.f;
  }
  __syncthreads();
  for(int it=t; it<P*CPAD; it+=256){
    int p = it/CPAD, c = it - p*CPAD;
    u32 u[8];
    if(c < CIN){
      float g[KNN];
      if(c < CPTS){
#pragma unroll
        for(int k=0;k<KNN;k++)
          g[k] = xin[(size_t)((b<<13) + si[p][k])*XSTRIDE + c];
        if(BN){
          float sm = bnst[c], sr = bnst[128+c];
#pragma unroll
          for(int k=0;k<KNN;k++){
            float v = (g[k]-sm)*sr;
            g[k] = v>=0.f? v : 0.1f*v;
          }
        }
      } else {
        int cc = c - CPTS;
#pragma unroll
        for(int k=0;k<KNN;k++) g[k] = gxs[p][k][cc];
      }
      float a[16];
#pragma unroll
      for(int wn=0; wn<16; wn++){
        float s = 0.f;
#pragma unroll
        for(int k=0;k<KNN;k++) s = fmaf(g[k], wm[p][k][wn], s);
        a[wn] = s;
      }
#pragma unroll
      for(int j=0;j<8;j++)
        u[j] = (u32)f2b(a[2*j]) | ((u32)f2b(a[2*j+1])<<16);
    } else {
#pragma unroll
      for(int j=0;j<8;j++) u[j]=0;
    }
    u32* dst = (u32*)(Abuf + ((size_t)(blockIdx.x*P + p)*KP + c*16));
    *(uint4*)dst       = make_uint4(u[0],u[1],u[2],u[3]);
    *((uint4*)dst + 1) = make_uint4(u[4],u[5],u[6],u[7]);
  }
}

// ---------------- MFMA GEMM (single-W, 8 waves) + fused bn stats ----------------
__device__ __forceinline__ void gload16(const void* g, void* l){
  __builtin_amdgcn_global_load_lds(
      (const __attribute__((address_space(1))) u32*)g,
      (__attribute__((address_space(3))) u32*)l, 16, 0, 0);
}

template<int KP>
__global__ __launch_bounds__(512) void k_gemm(
    const u16* __restrict__ Wh, const u16* __restrict__ A,
    const float* __restrict__ linb, float* __restrict__ outp,
    float* __restrict__ partial, int ptBase)
{
  __shared__ __attribute__((aligned(16))) u16 lds[24576];
  constexpr int NT = KP/64;
  int t = threadIdx.x, wave = t>>6, lane = t&63;
  int p0 = blockIdx.x*64;
  const u16* Ab = A + (size_t)p0*KP;

  auto stage = [&](const u16* __restrict__ g, int k0, int ldsByteOff, int rows){
    int nr = (rows*128) >> 13;
    for(int r=0;r<nr;r++){
      int y  = (r*8 + wave) << 10;
      int yl = y + lane*16;
      int row = yl >> 7;
      int s = (yl >> 4) & 7;
      int c = s ^ (row & 7);
      const u16* src = g + (size_t)row*KP + k0 + c*8;
      gload16(src, (char*)lds + ldsByteOff + y);
    }
  };

  stage(Wh, 0, 0,     128);
  stage(Ab, 0, 32768, 64);

  f32x4 acc[4];
#pragma unroll
  for(int j=0;j<4;j++) acc[j]=(f32x4)(0.f);

  for(int kt=0; kt<NT; kt++){
    int cur = kt & 1;
    __syncthreads();
    if(kt+1 < NT){
      int nxt = cur^1;
      stage(Wh, (kt+1)*64, nxt*16384,         128);
      stage(Ab, (kt+1)*64, 32768 + nxt*8192,  64);
    }
    const u16* Lw = lds + cur*8192;
    const u16* La = lds + 16384 + cur*4096;
#pragma unroll
    for(int kf=0; kf<2; kf++){
      int cb = kf*4 + (lane>>4);
      bf16x8 af[4];
#pragma unroll
      for(int nf=0; nf<4; nf++){
        int p = nf*16 + (lane&15);
        af[nf] = *(const bf16x8*)(La + p*64 + ((cb ^ (p&7))<<3));
      }
      int row = wave*16 + (lane&15);
      bf16x8 wh = *(const bf16x8*)(Lw + row*64 + ((cb ^ (row&7))<<3));
#pragma unroll
      for(int nf=0; nf<4; nf++)
        acc[nf] = __builtin_amdgcn_mfma_f32_16x16x32_bf16(wh, af[nf], acc[nf], 0,0,0);
    }
  }

  int gb = (ptBase>>6) + blockIdx.x;
  int q = lane>>4, lc = lane&15;
  int obase = wave*16 + q*4;
#pragma unroll
  for(int r=0;r<4;r++){
    int o = obase + r;
    float bo = linb[o];
    float sv = 0.f, qv = 0.f;
#pragma unroll
    for(int nf=0; nf<4; nf++){
      float x = acc[nf][r] + bo;
      outp[(size_t)(ptBase + p0 + nf*16 + lc)*128 + o] = x;
      sv += x; qv = fmaf(x,x,qv);
    }
#pragma unroll
    for(int off=8; off>0; off>>=1){
      sv += __shfl_down(sv,off);
      qv += __shfl_down(qv,off);
    }
    if(lc==0){
      partial[gb*256 + o]       = sv;
      partial[gb*256 + 128 + o] = qv;
    }
  }
}

// ---------------- fused mlp0 + mlp1 + fc (8 waves), bn+leaky on input ----------------
__global__ __launch_bounds__(512) void k_mlp(
    const float* __restrict__ outp1, const float* __restrict__ sto,
    const float* __restrict__ W0, const float* __restrict__ B0,
    const float* __restrict__ W1, const float* __restrict__ B1,
    const float* __restrict__ Wf, const float* __restrict__ Bf,
    float* __restrict__ dout)
{
  __shared__ float w0l[128*129];
  __shared__ float w1l[128*65];
  __shared__ float xt [128*65];
  __shared__ float m1l[64*65];
  int t = threadIdx.x;
  int pt0 = blockIdx.x*64;
  int b = pt0 >> 13, n0 = pt0 & (NPTS-1);
  for(int e=t; e<128*128; e+=512){ int o=e>>7, j=e&127; w0l[j*129+o] = W0[e]; }
  for(int e=t; e<64*128;  e+=512){ int o=e>>7, j=e&127; w1l[j*65+o]  = W1[e]; }
  for(int e=t; e<64*128;  e+=512){
    int p=e>>7, j=e&127;
    float v = outp1[(size_t)(pt0+p)*128 + j];
    v = (v - sto[j])*sto[128+j];
    xt[j*65+p] = v>=0.f? v : 0.1f*v;
  }
  __syncthreads();
  int p = t&63, wv = t>>6;
  float acc[16];
#pragma unroll
  for(int i=0;i<16;i++) acc[i]=0.f;
  for(int j=0;j<128;j++){
    float xv = xt[j*65+p];
#pragma unroll
    for(int i=0;i<16;i++)
      acc[i] = fmaf(w0l[j*129 + wv*16 + i], xv, acc[i]);
  }
  __syncthreads();
#pragma unroll
  for(int i=0;i<16;i++){
    int o = wv*16+i;
    float v = acc[i] + B0[o];
    v = v>=0.f? v : 0.1f*v;
    xt[o*65 + p] = v;
  }
  __syncthreads();
  float a2[8];
#pragma unroll
  for(int i=0;i<8;i++) a2[i]=0.f;
  for(int j=0;j<128;j++){
    float xv = xt[j*65+p];
#pragma unroll
    for(int i=0;i<8;i++)
      a2[i] = fmaf(w1l[j*65 + wv*8 + i], xv, a2[i]);
  }
#pragma unroll
  for(int i=0;i<8;i++){
    int o = wv*8+i;
    float v = a2[i] + B1[o];
    v = v>=0.f? v : 0.1f*v;
    dout[(size_t)(b*64+o)*NPTS + n0 + p] = v;
    m1l[o*65+p] = v;
  }
  __syncthreads();
  if(t < 192){
    int o = t/64, pp = t%64;
    float a = Bf[o];
    for(int j=0;j<64;j++) a = fmaf(Wf[o*64+j], m1l[j*65+pp], a);
    a = fminf(fmaxf(a, -200.f), 200.f);
    dout[(size_t)NBATCH*64*NPTS + (size_t)(b*3+o)*NPTS + n0 + pp] = a;
  }
}

extern "C" void kernel_launch(void* const* d_in, const int* in_sizes, int n_in,
                              void* d_out, int out_size, void* d_ws, size_t ws_size,
                              hipStream_t stream)
{
  (void)in_sizes; (void)n_in; (void)out_size;
  const float* xyz   = (const float*)d_in[0];
  const float* feats = (const float*)d_in[1];
  const float* cost  = (const float*)d_in[2];
  const float* flow  = (const float*)d_in[3];
  const float* pw1[2]  = {(const float*)d_in[4],  (const float*)d_in[12]};
  const float* pb1[2]  = {(const float*)d_in[5],  (const float*)d_in[13]};
  const float* pw2[2]  = {(const float*)d_in[6],  (const float*)d_in[14]};
  const float* pb2[2]  = {(const float*)d_in[7],  (const float*)d_in[15]};
  const float* pw3[2]  = {(const float*)d_in[8],  (const float*)d_in[16]};
  const float* pb3[2]  = {(const float*)d_in[9],  (const float*)d_in[17]};
  const float* plW[2]  = {(const float*)d_in[10], (const float*)d_in[18]};
  const float* plb[2]  = {(const float*)d_in[11], (const float*)d_in[19]};
  const float* m0W = (const float*)d_in[20];
  const float* m0b = (const float*)d_in[21];
  const float* m1W = (const float*)d_in[22];
  const float* m1b = (const float*)d_in[23];
  const float* fcW = (const float*)d_in[24];
  const float* fcb = (const float*)d_in[25];
  float* out = (float*)d_out;

  const int KP0 = 3200;
  const int KP1 = 2112;

  float* ws = (float*)d_ws;
  size_t o = 0;
  float* xin0 = ws + o; o += (size_t)NPT*196;
  int*   idx  = (int*)(ws + o); o += (size_t)NPT*KNN + 3;
  o &= ~(size_t)3;
  float4* xs  = (float4*)(ws + o); o += (size_t)NPT*4;
  float* thr  = ws + o; o += (size_t)NPT;
  int*   pi   = (int*)(ws + o); o += (size_t)NPT*SEG*KNN;
  float* h2a  = ws + o; o += (size_t)NPT*KNN*8;
  float* h2b  = ws + o; o += (size_t)NPT*KNN*8;
  float* wpre0 = ws + o; o += (size_t)NPT*KNN*16;
  float* wpre1 = ws + o; o += (size_t)NPT*KNN*16;
  float* gpart = ws + o; o += 64*9 + 7;
  float* part2a = ws + o; o += 576*16;
  float* part2b = ws + o; o += 576*16;
  float* part3a = ws + o; o += 576*32;
  float* part3b = ws + o; o += 576*32;
  float* parto = ws + o; o += 65536;
  float* st3a = ws + o; o += 32;
  float* st3b = ws + o; o += 32;
  float* sto0 = ws + o; o += 256;
  float* sto1 = ws + o; o += 256;
  float* outp0 = ws + o; o += (size_t)NPT*128;
  float* outp1 = ws + o; o += (size_t)NPT*128;
  u16* Wh0 = (u16*)(ws + o); o += (size_t)128*KP0/2;
  u16* Wh1 = (u16*)(ws + o); o += (size_t)128*KP1/2;
  u16* Abuf = (u16*)(ws + o);
  size_t used_bytes = o*4;
  size_t avail = ws_size > used_bytes ? ws_size - used_bytes : 0;
  int npc = NPT;
  while(npc > 1024 && (size_t)npc*KP0*2 > avail) npc >>= 1;

  k_build_xin<<<NPT/64, 256, 0, stream>>>(feats, cost, flow, xyz, xin0, xs);
  k_thr<<<256, 256, 0, stream>>>(xs, thr);
  k_knn_part<<<64*SEG, 256, 0, stream>>>(xs, thr, pi);
  k_knn_merge<<<NPT/256, 256, 0, stream>>>(xs, pi, idx, gpart);

  k_prepW2<<<(128*(KP0+KP1)+255)/256, 256, 0, stream>>>(plW[0], Wh0, plW[1], Wh1);

  const float cnt1 = (float)(NPT*KNN);
  const float cnto = (float)NPT;

  k_wn23a2<<<576,256,0,stream>>>(xyz, idx, gpart, cnt1,
                                 pw1[0], pb1[0], pw2[0], pb2[0],
                                 pw1[1], pb1[1], pw2[1], pb2[1],
                                 h2a, h2b, part2a, part2b);
  k_wn23_2<<<576,256,0,stream>>>(h2a, part2a, h2b, part2b, 576, cnt1,
                                 pw3[0], pb3[0], pw3[1], pb3[1],
                                 wpre0, wpre1, part3a, part3b);
  k_fin2<<<1,256,0,stream>>>(part3a, part3b, st3a, st3b, 576, cnt1);

  for(int c0 = 0; c0 < NPT; c0 += npc){
    k_buildA<198,196,KP0,false><<<npc/16,256,0,stream>>>(xin0, xyz, idx, wpre0, st3a, sto0, Abuf, c0);
    k_gemm<KP0><<<npc/64,512,0,stream>>>(Wh0, Abuf, plb[0], outp0, parto, c0);
  }
  k_fin<<<1,256,0,stream>>>(parto, sto0, 128, NPT/64, cnto);

  for(int c0 = 0; c0 < NPT; c0 += npc){
    k_buildA<131,128,KP1,true><<<npc/16,256,0,stream>>>(outp0, xyz, idx, wpre1, st3b, sto0, Abuf, c0);
    k_gemm<KP1><<<npc/64,512,0,stream>>>(Wh1, Abuf, plb[1], outp1, parto, c0);
  }
  k_fin<<<1,256,0,stream>>>(parto, sto1, 128, NPT/64, cnto);

  k_mlp<<<NPT/64,512,0,stream>>>(outp1, sto1, m0W,m0b, m1W,m1b, fcW,fcb, out);
}

// Round 13
// 520.176 us; speedup vs baseline: 1.1152x; 1.1152x over previous
//
#include <hip/hip_runtime.h>

#define NBATCH 2
#define NPTS   8192
#define NPT    (NBATCH*NPTS)
#define KNN    9
#define SEG    16
#define SEGN   (NPTS/SEG)
#define SSTR   20

typedef unsigned short u16;
typedef unsigned int   u32;
typedef short bf16x8 __attribute__((ext_vector_type(8)));
typedef float f32x4  __attribute__((ext_vector_type(4)));

__device__ __forceinline__ float wred(float v){
#pragma unroll
  for(int o=32;o>0;o>>=1) v += __shfl_down(v,o);
  return v;
}

__device__ __forceinline__ u16 f2b(float f){
  u32 u = __float_as_uint(f);
  return (u16)((u + 0x7fffu + ((u>>16)&1u)) >> 16);
}

__device__ __forceinline__ float bumpup(float x){
  u32 u = __float_as_uint(x);
  if(u == 0x80000000u) u = 1u;
  else if((int)u >= 0) u += 1u;
  else u -= 1u;
  return __uint_as_float(u);
}

// ---------------- build point-major feature matrix [pt][196] + xs table ----------------
__global__ __launch_bounds__(256) void k_build_xin(
    const float* __restrict__ feats, const float* __restrict__ cost,
    const float* __restrict__ flow, const float* __restrict__ xyz,
    float* __restrict__ xin, float4* __restrict__ xs)
{
  __shared__ float buf[196][67];
  int t = threadIdx.x;
  int pt0 = blockIdx.x*64;
  int b = pt0 >> 13, n0 = pt0 & (NPTS-1);
  int lane = t & 63, grp = t >> 6;
  const float* f  = feats + (size_t)b*128*NPTS + n0 + lane;
  const float* cv = cost  + (size_t)b*64 *NPTS + n0 + lane;
  const float* fl = flow  + (size_t)b*3  *NPTS + n0 + lane;
  for(int c=grp; c<128; c+=4) buf[c][lane]      = f[(size_t)c*NPTS];
  for(int c=grp; c<64;  c+=4) buf[128+c][lane]  = cv[(size_t)c*NPTS];
  if(grp<3) buf[192+grp][lane] = fl[(size_t)grp*NPTS];
  else      buf[195][lane] = 0.f;
  if(t < 64){
    int pt = pt0 + t;
    const float* p = xyz + (size_t)b*NPTS*3 + 3*(pt & (NPTS-1));
    float x=p[0], y=p[1], z=p[2];
    float s = __fadd_rn(__fadd_rn(__fmul_rn(x,x),__fmul_rn(y,y)),__fmul_rn(z,z));
    xs[pt] = make_float4(x,y,z,s);
  }
  __syncthreads();
  for(int e=t; e<64*49; e+=256){
    int p = e/49, q = e-p*49;
    float4 v = make_float4(buf[4*q][p], buf[4*q+1][p], buf[4*q+2][p], buf[4*q+3][p]);
    *(float4*)(xin + (size_t)(pt0+p)*196 + 4*q) = v;
  }
}

// ---------------- knn pass A: 9th-smallest over stride-16 sample (1024 blocks) ----------------
__global__ __launch_bounds__(256) void k_thr(
    const float4* __restrict__ xs, float* __restrict__ thr)
{
  __shared__ float md[16][16][9];      // [query][chunk][9]
  int t = threadIdx.x;
  int q = t & 15, chunk = t >> 4;
  int qb = blockIdx.x;                 // 0..1023
  int b = qb >> 9;
  int n = (qb & 511)*16 + q;
  const float4* xb4 = xs + (size_t)b*NPTS;
  float4 Q = xb4[n];
  float qx=Q.x, qy=Q.y, qz=Q.z, qs=Q.w;
  float bd[KNN];
#pragma unroll
  for(int i=0;i<KNN;i++) bd[i]=__builtin_inff();
  for(int i=0;i<32;i++){
    int m = (chunk*32 + i)*16;
    float4 c = xb4[m];
    float dot = fmaf(c.z,qz, fmaf(c.y,qy, __fmul_rn(c.x,qx)));
    float d = __fsub_rn(__fadd_rn(qs,c.w), __fmul_rn(2.0f,dot));
    if(d < bd[KNN-1]){
      bd[KNN-1]=d;
#pragma unroll
      for(int r=KNN-2;r>=0;r--){
        if(bd[r+1] < bd[r]){ float td=bd[r]; bd[r]=bd[r+1]; bd[r+1]=td; }
      }
    }
  }
#pragma unroll
  for(int i=0;i<KNN;i++) md[q][chunk][i]=bd[i];
  __syncthreads();
  if(t < 16){
    float b2[KNN];
#pragma unroll
    for(int i=0;i<KNN;i++) b2[i]=__builtin_inff();
    for(int w=0;w<16;w++){
#pragma unroll
      for(int i=0;i<KNN;i++){
        float d = md[t][w][i];
        if(d < b2[KNN-1]){
          b2[KNN-1]=d;
#pragma unroll
          for(int r=KNN-2;r>=0;r--){
            if(b2[r+1] < b2[r]){ float td=b2[r]; b2[r]=b2[r+1]; b2[r+1]=td; }
          }
        }
      }
    }
    thr[(b<<13) + (qb & 511)*16 + t] = b2[KNN-1];
  }
}

// ---------------- knn pass B: push-buffer top-9, hoisted flush check ----------------
__global__ __launch_bounds__(256) void k_knn_part(
    const float4* __restrict__ xs, const float* __restrict__ thr,
    float* __restrict__ pd, int* __restrict__ pi)
{
  __shared__ float sdq[256*SSTR];
  __shared__ int   sqi[256*SSTR];
  int t = threadIdx.x;
  int seg = blockIdx.x & (SEG-1);
  int qc  = blockIdx.x >> 4;
  int b = qc >> 5;
  int n = (qc & 31)*256 + t;
  int pt = (b<<13) + n;
  const float4* xb4 = xs + (size_t)b*NPTS;
  float4 q = xb4[n];
  float qx=q.x, qy=q.y, qz=q.z, qs=q.w;
  float init = bumpup(thr[pt]);
  float bd[KNN]; int bi[KNN];
#pragma unroll
  for(int i=0;i<KNN;i++){ bd[i]=init; bi[i]=0x7fffffff; }
  float cut = init;
  int cnt = 0;
  float* msd = sdq + t*SSTR;
  int*   msi = sqi + t*SSTR;
  auto flush = [&](){
    for(int i=0;i<cnt;i++){
      float d = msd[i]; int id = msi[i];
      if(d < bd[KNN-1]){
        bd[KNN-1]=d; bi[KNN-1]=id;
#pragma unroll
        for(int r=KNN-2;r>=0;r--){
          if(bd[r+1] < bd[r]){
            float td=bd[r]; bd[r]=bd[r+1]; bd[r+1]=td;
            int ti=bi[r]; bi[r]=bi[r+1]; bi[r+1]=ti;
          }
        }
      }
    }
    cnt = 0;
    cut = bd[KNN-1];
  };
  const int m0 = seg*SEGN;
  for(int j0=0; j0<SEGN; j0+=8){
    if(cnt > SSTR-8) flush();
    float dv[8];
#pragma unroll
    for(int u=0;u<8;u++){
      float4 c = xb4[m0+j0+u];                 // wave-uniform address -> broadcast
      float dot = fmaf(c.z,qz, fmaf(c.y,qy, __fmul_rn(c.x,qx)));
      dv[u] = __fsub_rn(__fadd_rn(qs,c.w), __fmul_rn(2.0f,dot));
    }
#pragma unroll
    for(int u=0;u<8;u++){
      if(dv[u] < cut){
        msd[cnt]=dv[u]; msi[cnt]=m0+j0+u; cnt++;
      }
    }
  }
  flush();
  size_t base = ((size_t)pt*SEG + seg)*KNN;
#pragma unroll
  for(int i=0;i<KNN;i++){ pd[base+i]=bd[i]; pi[base+i]=bi[i]; }
}

// ---------------- merge (pd-based) + g-moment partials ----------------
__global__ __launch_bounds__(256) void k_knn_merge(
    const float4* __restrict__ xs,
    const float* __restrict__ pd, const int* __restrict__ pi,
    int* __restrict__ idxo, float* __restrict__ gpart)
{
  __shared__ float red[4][9];
  int t = threadIdx.x;
  int pt = blockIdx.x*256 + t;
  int b = pt >> 13;
  const float4* xb4 = xs + (size_t)b*NPTS;
  float4 q = xb4[pt & (NPTS-1)];
  const float4* dp = (const float4*)(pd + (size_t)pt*SEG*KNN);
  const int4*   ip = (const int4*)(pi + (size_t)pt*SEG*KNN);
  float bd[KNN]; int bi[KNN];
#pragma unroll
  for(int i=0;i<KNN;i++){ bd[i]=__builtin_inff(); bi[i]=0x7fffffff; }
  for(int v=0; v<SEG*KNN/4; v++){
    float4 dv = dp[v];
    int4   iv = ip[v];
    float dd[4] = {dv.x,dv.y,dv.z,dv.w};
    int   ii[4] = {iv.x,iv.y,iv.z,iv.w};
#pragma unroll
    for(int u=0;u<4;u++){
      float d = dd[u]; int id = ii[u];
      if(d < bd[KNN-1]){
        bd[KNN-1]=d; bi[KNN-1]=id;
#pragma unroll
        for(int i=KNN-2;i>=0;i--){
          if(bd[i+1] < bd[i]){
            float td=bd[i]; bd[i]=bd[i+1]; bd[i+1]=td;
            int ti=bi[i]; bi[i]=bi[i+1]; bi[i+1]=ti;
          }
        }
      }
    }
  }
#pragma unroll
  for(int r=0;r<KNN;r++) idxo[pt*KNN + r] = bi[r];
  float mom[9];
#pragma unroll
  for(int i=0;i<9;i++) mom[i]=0.f;
#pragma unroll
  for(int r=0;r<KNN;r++){
    int m = bi[r];
    float4 c = xb4[m];
    float gx=c.x-q.x, gy=c.y-q.y, gz=c.z-q.z;
    mom[0]+=gx; mom[1]+=gy; mom[2]+=gz;
    mom[3]=fmaf(gx,gx,mom[3]); mom[4]=fmaf(gy,gy,mom[4]); mom[5]=fmaf(gz,gz,mom[5]);
    mom[6]=fmaf(gx,gy,mom[6]); mom[7]=fmaf(gx,gz,mom[7]); mom[8]=fmaf(gy,gz,mom[8]);
  }
  int wave = t>>6, lane = t&63;
#pragma unroll
  for(int i=0;i<9;i++){
    float s = wred(mom[i]);
    if(lane==0) red[wave][i]=s;
  }
  __syncthreads();
  if(t<9)
    gpart[blockIdx.x*9 + t] = red[0][t]+red[1][t]+red[2][t]+red[3][t];
}

// ---------------- wn stage1+2 fused, BOTH layers ----------------
__global__ __launch_bounds__(256) void k_wn23a2(
    const float* __restrict__ xyz, const int* __restrict__ idx,
    const float* __restrict__ gpart, float cnt,
    const float* __restrict__ W1a, const float* __restrict__ B1a,
    const float* __restrict__ W2a, const float* __restrict__ B2a,
    const float* __restrict__ W1b, const float* __restrict__ B1b,
    const float* __restrict__ W2b, const float* __restrict__ B2b,
    float* __restrict__ houta, float* __restrict__ houtb,
    float* __restrict__ parta, float* __restrict__ partb)
{
  __shared__ float mom[9];
  __shared__ float stl[2][16];
  __shared__ float red[4][2][8];
  int t = threadIdx.x;
  if(t<9){
    float s=0.f;
    for(int r=0;r<64;r++) s += gpart[r*9+t];
    mom[t]=s;
  }
  __syncthreads();
  if(t<16){
    int L = t>>3, j = t&7;
    const float* W1 = L? W1b : W1a;
    const float* B1 = L? B1b : B1a;
    float inv = 1.0f/cnt;
    float w0=W1[3*j], w1=W1[3*j+1], w2=W1[3*j+2], bb=B1[j];
    float Eg0=mom[0]*inv, Eg1=mom[1]*inv, Eg2=mom[2]*inv;
    float Mxx=mom[3]*inv, Myy=mom[4]*inv, Mzz=mom[5]*inv;
    float Mxy=mom[6]*inv, Mxz=mom[7]*inv, Myz=mom[8]*inv;
    float mu_lin = w0*Eg0 + w1*Eg1 + w2*Eg2;
    float mean = mu_lin + bb;
    float e2 = w0*w0*Mxx + w1*w1*Myy + w2*w2*Mzz
             + 2.f*(w0*w1*Mxy + w0*w2*Mxz + w1*w2*Myz)
             + 2.f*bb*mu_lin + bb*bb;
    float var = e2 - mean*mean;
    stl[L][j] = mean;
    stl[L][8+j] = 1.0f/sqrtf(var + 1e-5f);
  }
  __syncthreads();
  int e = blockIdx.x*256 + t;
  int pt = e/KNN;
  int b = pt>>13, n = pt & (NPTS-1);
  int m = idx[e];
  const float* xb = xyz + (size_t)b*NPTS*3;
  float gx = xb[3*m]-xb[3*n], gy = xb[3*m+1]-xb[3*n+1], gz = xb[3*m+2]-xb[3*n+2];
  int wave = t>>6, lane = t&63;
#pragma unroll
  for(int L=0; L<2; L++){
    const float* W1 = L? W1b : W1a;
    const float* B1 = L? B1b : B1a;
    const float* W2 = L? W2b : W2a;
    const float* B2 = L? B2b : B2a;
    float* hout = L? houtb : houta;
    float* part = L? partb : parta;
    float x[8];
#pragma unroll
    for(int j=0;j<8;j++){
      float d = fmaf(gz, W1[3*j+2], fmaf(gy, W1[3*j+1], gx*W1[3*j]));
      float v = d + B1[j];
      v = (v - stl[L][j])*stl[L][8+j];
      x[j] = v>0.f? v : 0.f;
    }
    float v[8];
#pragma unroll
    for(int j=0;j<8;j++){
      float d = 0.f;
#pragma unroll
      for(int i=0;i<8;i++) d = fmaf(x[i], W2[j*8+i], d);
      v[j] = d + B2[j];
      hout[(size_t)e*8 + j] = v[j];
    }
#pragma unroll
    for(int j=0;j<8;j++){
      float s = wred(v[j]);
      float q = wred(v[j]*v[j]);
      if(lane==0){ red[wave][0][j]=s; red[wave][1][j]=q; }
    }
    __syncthreads();
    if(t < 16){
      int isq = t>>3, c = t&7;
      part[blockIdx.x*16 + t] =
        red[0][isq][c]+red[1][isq][c]+red[2][isq][c]+red[3][isq][c];
    }
    __syncthreads();
  }
}

// ---------------- wn stage 3, BOTH layers ----------------
__global__ __launch_bounds__(256) void k_wn23_2(
    const float* __restrict__ hina, const float* __restrict__ pina,
    const float* __restrict__ hinb, const float* __restrict__ pinb,
    int nb, float cnt,
    const float* __restrict__ Wa, const float* __restrict__ Ba,
    const float* __restrict__ Wb, const float* __restrict__ Bb,
    float* __restrict__ houta, float* __restrict__ houtb,
    float* __restrict__ parta, float* __restrict__ partb)
{
  __shared__ float sa[256], qa[256];
  __shared__ float stl[16];
  __shared__ float red[4][2][16];
  int t = threadIdx.x;
  int e = blockIdx.x*256 + t;
  int wave = t>>6, lane = t&63;
#pragma unroll
  for(int L=0; L<2; L++){
    const float* hin = L? hinb : hina;
    const float* pin = L? pinb : pina;
    const float* W   = L? Wb : Wa;
    const float* Bv  = L? Bb : Ba;
    float* hout = L? houtb : houta;
    float* part = L? partb : parta;
    {
      int c = t % 8;
      int r0 = t / 8;
      float s=0.f, q=0.f;
      for(int r=r0; r<nb; r+=32){
        s += pin[r*16 + c];
        q += pin[r*16 + 8 + c];
      }
      sa[t]=s; qa[t]=q;
      __syncthreads();
      if(t < 8){
        for(int g=1; g<32; g++){ s += sa[t+g*8]; q += qa[t+g*8]; }
        float mean = s/cnt;
        float var  = q/cnt - mean*mean;
        stl[t]   = mean;
        stl[8+t] = 1.0f/sqrtf(var + 1e-5f);
      }
      __syncthreads();
    }
    float x[8];
#pragma unroll
    for(int i=0;i<8;i++){
      float v = (hin[(size_t)e*8 + i] - stl[i])*stl[8+i];
      x[i] = v>0.f? v : 0.f;
    }
    float v[16];
#pragma unroll
    for(int j=0;j<16;j++){
      float d = 0.f;
#pragma unroll
      for(int i=0;i<8;i++) d = fmaf(x[i], W[j*8+i], d);
      v[j] = d + Bv[j];
      hout[(size_t)e*16 + j] = v[j];
    }
#pragma unroll
    for(int j=0;j<16;j++){
      float s = wred(v[j]);
      float q = wred(v[j]*v[j]);
      if(lane==0){ red[wave][0][j]=s; red[wave][1][j]=q; }
    }
    __syncthreads();
    if(t < 32){
      int isq = t>>4, c = t&15;
      part[blockIdx.x*32 + t] =
        red[0][isq][c]+red[1][isq][c]+red[2][isq][c]+red[3][isq][c];
    }
    __syncthreads();
  }
}

// ---------------- finalize st3 for both layers ----------------
__global__ __launch_bounds__(256) void k_fin2(
    const float* __restrict__ pa, const float* __restrict__ pb,
    float* __restrict__ sta, float* __restrict__ stb, int nb, float cnt)
{
  __shared__ float sa[256], qa[256];
  int t = threadIdx.x;
  const int C = 16;
#pragma unroll
  for(int L=0; L<2; L++){
    const float* partial = L? pb : pa;
    float* st = L? stb : sta;
    int c = t % C;
    int r0 = t / C;
    int stride = 256 / C;
    float s=0.f, q=0.f;
    for(int r=r0; r<nb; r+=stride){
      s += partial[r*2*C + c];
      q += partial[r*2*C + C + c];
    }
    sa[t]=s; qa[t]=q;
    __syncthreads();
    if(t < C){
      for(int g=1; g<stride; g++){ s += sa[t+g*C]; q += qa[t+g*C]; }
      float mean = s/cnt;
      float var  = q/cnt - mean*mean;
      st[t]   = mean;
      st[C+t] = 1.0f/sqrtf(var + 1e-5f);
    }
    __syncthreads();
  }
}

// ---------------- finalize stats (generic) ----------------
__global__ __launch_bounds__(256) void k_fin(
    const float* __restrict__ partial, float* __restrict__ st,
    int C, int nb, float cnt)
{
  __shared__ float sa[256], qa[256];
  int t = threadIdx.x;
  int c = t % C;
  int r0 = t / C;
  int stride = 256 / C;
  float s=0.f, q=0.f;
  for(int r=r0; r<nb; r+=stride){
    s += partial[r*2*C + c];
    q += partial[r*2*C + C + c];
  }
  sa[t]=s; qa[t]=q;
  __syncthreads();
  if(t < C){
    for(int g=1; g<stride; g++){ s += sa[t+g*C]; q += qa[t+g*C]; }
    float mean = s/cnt;
    float var  = q/cnt - mean*mean;
    st[t]   = mean;
    st[C+t] = 1.0f/sqrtf(var + 1e-5f);
  }
}

// ---------------- prep both W: f32 -> bf16, K-padded ----------------
__global__ __launch_bounds__(256) void k_prepW2(
    const float* __restrict__ W0, u16* __restrict__ Wh0,
    const float* __restrict__ W1, u16* __restrict__ Wh1)
{
  int e = blockIdx.x*256 + threadIdx.x;
  const int N0 = 128*3200;
  if(e < N0){
    int o = e / 3200, k = e - o*3200;
    float w = (k < 3168) ? W0[o*3168 + k] : 0.f;
    Wh0[e] = f2b(w);
  } else {
    int e1 = e - N0;
    if(e1 >= 128*2112) return;
    int o = e1 / 2112, k = e1 - o*2112;
    float w = (k < 2096) ? W1[o*2096 + k] : 0.f;
    Wh1[e1] = f2b(w);
  }
}

// ---------------- build A (gather [+bn+leaky] + weightnet einsum) ----------------
template<int CIN, int XSTRIDE, int KP, bool BN>
__global__ __launch_bounds__(256) void k_buildA(
    const float* __restrict__ xin, const float* __restrict__ xyz,
    const int* __restrict__ idx, const float* __restrict__ wpre,
    const float* __restrict__ st3, const float* __restrict__ bnst,
    u16* __restrict__ Abuf, int c0)
{
  constexpr int P = 16;
  constexpr int CPTS = CIN-3;
  constexpr int CPAD = KP/16;
  __shared__ float wm[P][KNN][16];
  __shared__ float gxs[P][KNN][3];
  __shared__ int   si[P][KNN];
  __shared__ float sm3[16], sr3[16];
  int t = threadIdx.x;
  int pt0 = c0 + blockIdx.x*P;
  int b = pt0 >> 13;
  const float* xb = xyz + (size_t)b*NPTS*3;
  if(t<16){ sm3[t]=st3[t]; sr3[t]=st3[16+t]; }
  for(int e=t; e<P*KNN; e+=256){
    int p = e/KNN, k = e - p*KNN;
    int n = (pt0+p)&(NPTS-1);
    int m = idx[(pt0+p)*KNN+k];
    si[p][k]=m;
    gxs[p][k][0]=xb[3*m]  -xb[3*n];
    gxs[p][k][1]=xb[3*m+1]-xb[3*n+1];
    gxs[p][k][2]=xb[3*m+2]-xb[3*n+2];
  }
  __syncthreads();
  for(int e=t; e<P*KNN*16; e+=256){
    int p = e/(KNN*16); int r = e - p*(KNN*16); int k = r>>4, wn = r&15;
    float v = (wpre[((size_t)(pt0+p)*KNN + k)*16 + wn] - sm3[wn]) * sr3[wn];
    wm[p][k][wn] = v>0.f? v:0.f;
  }
  __syncthreads();
  for(int it=t; it<P*CPAD; it+=256){
    int p = it/CPAD, c = it - p*CPAD;
    u32 u[8];
    if(c < CIN){
      float g[KNN];
      if(c < CPTS){
#pragma unroll
        for(int k=0;k<KNN;k++)
          g[k] = xin[(size_t)((b<<13) + si[p][k])*XSTRIDE + c];
        if(BN){
          float sm = bnst[c], sr = bnst[128+c];
#pragma unroll
          for(int k=0;k<KNN;k++){
            float v = (g[k]-sm)*sr;
            g[k] = v>=0.f? v : 0.1f*v;
          }
        }
      } else {
        int cc = c - CPTS;
#pragma unroll
        for(int k=0;k<KNN;k++) g[k] = gxs[p][k][cc];
      }
      float a[16];
#pragma unroll
      for(int wn=0; wn<16; wn++){
        float s = 0.f;
#pragma unroll
        for(int k=0;k<KNN;k++) s = fmaf(g[k], wm[p][k][wn], s);
        a[wn] = s;
      }
#pragma unroll
      for(int j=0;j<8;j++)
        u[j] = (u32)f2b(a[2*j]) | ((u32)f2b(a[2*j+1])<<16);
    } else {
#pragma unroll
      for(int j=0;j<8;j++) u[j]=0;
    }
    u32* dst = (u32*)(Abuf + ((size_t)(blockIdx.x*P + p)*KP + c*16));
    *(uint4*)dst       = make_uint4(u[0],u[1],u[2],u[3]);
    *((uint4*)dst + 1) = make_uint4(u[4],u[5],u[6],u[7]);
  }
}

// ---------------- MFMA GEMM (single-W, 8 waves) + fused bn stats ----------------
__device__ __forceinline__ void gload16(const void* g, void* l){
  __builtin_amdgcn_global_load_lds(
      (const __attribute__((address_space(1))) u32*)g,
      (__attribute__((address_space(3))) u32*)l, 16, 0, 0);
}

template<int KP>
__global__ __launch_bounds__(512) void k_gemm(
    const u16* __restrict__ Wh, const u16* __restrict__ A,
    const float* __restrict__ linb, float* __restrict__ outp,
    float* __restrict__ partial, int ptBase)
{
  __shared__ __attribute__((aligned(16))) u16 lds[24576];
  constexpr int NT = KP/64;
  int t = threadIdx.x, wave = t>>6, lane = t&63;
  int p0 = blockIdx.x*64;
  const u16* Ab = A + (size_t)p0*KP;

  auto stage = [&](const u16* __restrict__ g, int k0, int ldsByteOff, int rows){
    int nr = (rows*128) >> 13;
    for(int r=0;r<nr;r++){
      int y  = (r*8 + wave) << 10;
      int yl = y + lane*16;
      int row = yl >> 7;
      int s = (yl >> 4) & 7;
      int c = s ^ (row & 7);
      const u16* src = g + (size_t)row*KP + k0 + c*8;
      gload16(src, (char*)lds + ldsByteOff + y);
    }
  };

  stage(Wh, 0, 0,     128);
  stage(Ab, 0, 32768, 64);

  f32x4 acc[4];
#pragma unroll
  for(int j=0;j<4;j++) acc[j]=(f32x4)(0.f);

  for(int kt=0; kt<NT; kt++){
    int cur = kt & 1;
    __syncthreads();
    if(kt+1 < NT){
      int nxt = cur^1;
      stage(Wh, (kt+1)*64, nxt*16384,         128);
      stage(Ab, (kt+1)*64, 32768 + nxt*8192,  64);
    }
    const u16* Lw = lds + cur*8192;
    const u16* La = lds + 16384 + cur*4096;
#pragma unroll
    for(int kf=0; kf<2; kf++){
      int cb = kf*4 + (lane>>4);
      bf16x8 af[4];
#pragma unroll
      for(int nf=0; nf<4; nf++){
        int p = nf*16 + (lane&15);
        af[nf] = *(const bf16x8*)(La + p*64 + ((cb ^ (p&7))<<3));
      }
      int row = wave*16 + (lane&15);
      bf16x8 wh = *(const bf16x8*)(Lw + row*64 + ((cb ^ (row&7))<<3));
#pragma unroll
      for(int nf=0; nf<4; nf++)
        acc[nf] = __builtin_amdgcn_mfma_f32_16x16x32_bf16(wh, af[nf], acc[nf], 0,0,0);
    }
  }

  int gb = (ptBase>>6) + blockIdx.x;
  int q = lane>>4, lc = lane&15;
  int obase = wave*16 + q*4;
#pragma unroll
  for(int r=0;r<4;r++){
    int o = obase + r;
    float bo = linb[o];
    float sv = 0.f, qv = 0.f;
#pragma unroll
    for(int nf=0; nf<4; nf++){
      float x = acc[nf][r] + bo;
      outp[(size_t)(ptBase + p0 + nf*16 + lc)*128 + o] = x;
      sv += x; qv = fmaf(x,x,qv);
    }
#pragma unroll
    for(int off=8; off>0; off>>=1){
      sv += __shfl_down(sv,off);
      qv += __shfl_down(qv,off);
    }
    if(lc==0){
      partial[gb*256 + o]       = sv;
      partial[gb*256 + 128 + o] = qv;
    }
  }
}

// ---------------- fused mlp0 + mlp1 + fc (8 waves), bn+leaky on input ----------------
__global__ __launch_bounds__(512) void k_mlp(
    const float* __restrict__ outp1, const float* __restrict__ sto,
    const float* __restrict__ W0, const float* __restrict__ B0,
    const float* __restrict__ W1, const float* __restrict__ B1,
    const float* __restrict__ Wf, const float* __restrict__ Bf,
    float* __restrict__ dout)
{
  __shared__ float w0l[128*129];
  __shared__ float w1l[128*65];
  __shared__ float xt [128*65];
  __shared__ float m1l[64*65];
  int t = threadIdx.x;
  int pt0 = blockIdx.x*64;
  int b = pt0 >> 13, n0 = pt0 & (NPTS-1);
  for(int e=t; e<128*128; e+=512){ int o=e>>7, j=e&127; w0l[j*129+o] = W0[e]; }
  for(int e=t; e<64*128;  e+=512){ int o=e>>7, j=e&127; w1l[j*65+o]  = W1[e]; }
  for(int e=t; e<64*128;  e+=512){
    int p=e>>7, j=e&127;
    float v = outp1[(size_t)(pt0+p)*128 + j];
    v = (v - sto[j])*sto[128+j];
    xt[j*65+p] = v>=0.f? v : 0.1f*v;
  }
  __syncthreads();
  int p = t&63, wv = t>>6;
  float acc[16];
#pragma unroll
  for(int i=0;i<16;i++) acc[i]=0.f;
  for(int j=0;j<128;j++){
    float xv = xt[j*65+p];
#pragma unroll
    for(int i=0;i<16;i++)
      acc[i] = fmaf(w0l[j*129 + wv*16 + i], xv, acc[i]);
  }
  __syncthreads();
#pragma unroll
  for(int i=0;i<16;i++){
    int o = wv*16+i;
    float v = acc[i] + B0[o];
    v = v>=0.f? v : 0.1f*v;
    xt[o*65 + p] = v;
  }
  __syncthreads();
  float a2[8];
#pragma unroll
  for(int i=0;i<8;i++) a2[i]=0.f;
  for(int j=0;j<128;j++){
    float xv = xt[j*65+p];
#pragma unroll
    for(int i=0;i<8;i++)
      a2[i] = fmaf(w1l[j*65 + wv*8 + i], xv, a2[i]);
  }
#pragma unroll
  for(int i=0;i<8;i++){
    int o = wv*8+i;
    float v = a2[i] + B1[o];
    v = v>=0.f? v : 0.1f*v;
    dout[(size_t)(b*64+o)*NPTS + n0 + p] = v;
    m1l[o*65+p] = v;
  }
  __syncthreads();
  if(t < 192){
    int o = t/64, pp = t%64;
    float a = Bf[o];
    for(int j=0;j<64;j++) a = fmaf(Wf[o*64+j], m1l[j*65+pp], a);
    a = fminf(fmaxf(a, -200.f), 200.f);
    dout[(size_t)NBATCH*64*NPTS + (size_t)(b*3+o)*NPTS + n0 + pp] = a;
  }
}

extern "C" void kernel_launch(void* const* d_in, const int* in_sizes, int n_in,
                              void* d_out, int out_size, void* d_ws, size_t ws_size,
                              hipStream_t stream)
{
  (void)in_sizes; (void)n_in; (void)out_size;
  const float* xyz   = (const float*)d_in[0];
  const float* feats = (const float*)d_in[1];
  const float* cost  = (const float*)d_in[2];
  const float* flow  = (const float*)d_in[3];
  const float* pw1[2]  = {(const float*)d_in[4],  (const float*)d_in[12]};
  const float* pb1[2]  = {(const float*)d_in[5],  (const float*)d_in[13]};
  const float* pw2[2]  = {(const float*)d_in[6],  (const float*)d_in[14]};
  const float* pb2[2]  = {(const float*)d_in[7],  (const float*)d_in[15]};
  const float* pw3[2]  = {(const float*)d_in[8],  (const float*)d_in[16]};
  const float* pb3[2]  = {(const float*)d_in[9],  (const float*)d_in[17]};
  const float* plW[2]  = {(const float*)d_in[10], (const float*)d_in[18]};
  const float* plb[2]  = {(const float*)d_in[11], (const float*)d_in[19]};
  const float* m0W = (const float*)d_in[20];
  const float* m0b = (const float*)d_in[21];
  const float* m1W = (const float*)d_in[22];
  const float* m1b = (const float*)d_in[23];
  const float* fcW = (const float*)d_in[24];
  const float* fcb = (const float*)d_in[25];
  float* out = (float*)d_out;

  const int KP0 = 3200;
  const int KP1 = 2112;

  float* ws = (float*)d_ws;
  size_t o = 0;
  float* xin0 = ws + o; o += (size_t)NPT*196;
  int*   idx  = (int*)(ws + o); o += (size_t)NPT*KNN + 3;
  o &= ~(size_t)3;
  float4* xs  = (float4*)(ws + o); o += (size_t)NPT*4;
  float* thr  = ws + o; o += (size_t)NPT;
  float* pd   = ws + o; o += (size_t)NPT*SEG*KNN;
  int*   pi   = (int*)(ws + o); o += (size_t)NPT*SEG*KNN;
  float* h2a  = ws + o; o += (size_t)NPT*KNN*8;
  float* h2b  = ws + o; o += (size_t)NPT*KNN*8;
  float* wpre0 = ws + o; o += (size_t)NPT*KNN*16;
  float* wpre1 = ws + o; o += (size_t)NPT*KNN*16;
  float* gpart = ws + o; o += 64*9 + 7;
  float* part2a = ws + o; o += 576*16;
  float* part2b = ws + o; o += 576*16;
  float* part3a = ws + o; o += 576*32;
  float* part3b = ws + o; o += 576*32;
  float* parto = ws + o; o += 65536;
  float* st3a = ws + o; o += 32;
  float* st3b = ws + o; o += 32;
  float* sto0 = ws + o; o += 256;
  float* sto1 = ws + o; o += 256;
  float* outp0 = ws + o; o += (size_t)NPT*128;
  float* outp1 = ws + o; o += (size_t)NPT*128;
  u16* Wh0 = (u16*)(ws + o); o += (size_t)128*KP0/2;
  u16* Wh1 = (u16*)(ws + o); o += (size_t)128*KP1/2;
  u16* Abuf = (u16*)(ws + o);
  size_t used_bytes = o*4;
  size_t avail = ws_size > used_bytes ? ws_size - used_bytes : 0;
  int npc = NPT;
  while(npc > 1024 && (size_t)npc*KP0*2 > avail) npc >>= 1;

  k_build_xin<<<NPT/64, 256, 0, stream>>>(feats, cost, flow, xyz, xin0, xs);
  k_thr<<<1024, 256, 0, stream>>>(xs, thr);
  k_knn_part<<<64*SEG, 256, 0, stream>>>(xs, thr, pd, pi);
  k_knn_merge<<<NPT/256, 256, 0, stream>>>(xs, pd, pi, idx, gpart);

  k_prepW2<<<(128*(KP0+KP1)+255)/256, 256, 0, stream>>>(plW[0], Wh0, plW[1], Wh1);

  const float cnt1 = (float)(NPT*KNN);
  const float cnto = (float)NPT;

  k_wn23a2<<<576,256,0,stream>>>(xyz, idx, gpart, cnt1,
                                 pw1[0], pb1[0], pw2[0], pb2[0],
                                 pw1[1], pb1[1], pw2[1], pb2[1],
                                 h2a, h2b, part2a, part2b);
  k_wn23_2<<<576,256,0,stream>>>(h2a, part2a, h2b, part2b, 576, cnt1,
                                 pw3[0], pb3[0], pw3[1], pb3[1],
                                 wpre0, wpre1, part3a, part3b);
  k_fin2<<<1,256,0,stream>>>(part3a, part3b, st3a, st3b, 576, cnt1);

  for(int c0 = 0; c0 < NPT; c0 += npc){
    k_buildA<198,196,KP0,false><<<npc/16,256,0,stream>>>(xin0, xyz, idx, wpre0, st3a, sto0, Abuf, c0);
    k_gemm<KP0><<<npc/64,512,0,stream>>>(Wh0, Abuf, plb[0], outp0, parto, c0);
  }
  k_fin<<<1,256,0,stream>>>(parto, sto0, 128, NPT/64, cnto);

  for(int c0 = 0; c0 < NPT; c0 += npc){
    k_buildA<131,128,KP1,true><<<npc/16,256,0,stream>>>(outp0, xyz, idx, wpre1, st3b, sto0, Abuf, c0);
    k_gemm<KP1><<<npc/64,512,0,stream>>>(Wh1, Abuf, plb[1], outp1, parto, c0);
  }
  k_fin<<<1,256,0,stream>>>(parto, sto1, 128, NPT/64, cnto);

  k_mlp<<<NPT/64,512,0,stream>>>(outp1, sto1, m0W,m0b, m1W,m1b, fcW,fcb, out);
}